// Round 8
// baseline (35.654 us; speedup 1.0000x reference)
//
#include <hip/hip_runtime.h>

typedef __attribute__((ext_vector_type(8)))  short short8;
typedef __attribute__((ext_vector_type(16))) float f32x16;

#define NPTS 2048
#define BATCH 32
#define NUM_CLASSES 6
#define THREADS 256
#define QPB 512               // queries per block (4 waves * 4 qtiles * 32)
#define QC 4                  // query chunks: 2048 / 512
#define GRID (2 * BATCH * QC) // 256 blocks
#define TSTRIDE 33            // transpose-buffer stride (conflict-free)
#define BF16_ONE ((short)0x3F80)

__device__ __forceinline__ unsigned short f2bf(float x) {
    union { float f; unsigned u; } v; v.f = x;
    unsigned r = v.u + 0x7FFF + ((v.u >> 16) & 1);   // RNE to bf16
    return (unsigned short)(r >> 16);
}
__device__ __forceinline__ float bf2f(unsigned short h) {
    union { unsigned u; float f; } v; v.u = ((unsigned)h) << 16; return v.f;
}

// K-slot plan (K=16): D = a2 + b2 - 2 a.b (hi/lo bf16 split, absmax-0 verified
// R3-R7). A row = lane&31, k = (lane>>5)*8+j ; B col = lane&31, same k split.
//  k0-2: A=ah B=-2bh | k3-5: A=al B=-2bh | k6-8: A=ah B=-2bl
//  k9: A=1 B=b2h | k10: A=1 B=b2l | k11: A=a2h B=1 | k12: A=a2l B=1 | k13-15: 0
__global__ __launch_bounds__(THREADS, 1) void chamfer_pass1(
    const float* __restrict__ inst, const float* __restrict__ model,
    float* __restrict__ partial)
{
    __shared__ char smem[QPB * TSTRIDE * 4];   // 67584 B; [0,64K) = cands staging
    __shared__ float wsum[4];

    const int blk   = blockIdx.x;
    const int qcc   = blk & 3;
    const int batch = (blk >> 2) & 31;
    const int dir   = blk >> 7;
    const int tid   = threadIdx.x;
    const int lane  = tid & 63, wid = tid >> 6;
    const int lh    = lane >> 5, lr = lane & 31;

    const float* __restrict__ Q  = dir ? model : inst;
    const float* __restrict__ Cp = dir ? inst  : model;

    // ---- stage ALL 2048 candidates of this batch into B-frag layout (64 KB) ----
    const float* cb = Cp + (size_t)batch * NPTS * 3;
    for (int c = tid; c < NPTS; c += THREADS) {
        float bx = cb[c*3+0], by = cb[c*3+1], bz = cb[c*3+2];
        float m2x = -2.f*bx, m2y = -2.f*by, m2z = -2.f*bz;
        unsigned short hx = f2bf(m2x), hy = f2bf(m2y), hz = f2bf(m2z);
        unsigned short lx = f2bf(m2x - bf2f(hx));
        unsigned short ly = f2bf(m2y - bf2f(hy));
        unsigned short lz = f2bf(m2z - bf2f(hz));
        float b2 = fmaf(bx,bx, fmaf(by,by, bz*bz));
        unsigned short b2h = f2bf(b2);
        unsigned short b2l = f2bf(b2 - bf2f(b2h));
        short8 kg0 = { (short)hx,(short)hy,(short)hz,(short)hx,(short)hy,(short)hz,(short)lx,(short)ly };
        short8 kg1 = { (short)lz,(short)b2h,(short)b2l, BF16_ONE, BF16_ONE, 0,0,0 };
        *(short8*)(smem + c*32)      = kg0;
        *(short8*)(smem + c*32 + 16) = kg1;
    }

    // ---- A-frags: 4 query tiles per wave (128 q/wave, 512 q/block) ----
    short8 af[4];
    const float* qb = Q + ((size_t)batch * NPTS + (size_t)qcc * QPB) * 3;
    #pragma unroll
    for (int qt = 0; qt < 4; ++qt) {
        const int qi = wid * 128 + qt * 32 + lr;
        float x = qb[qi*3+0], y = qb[qi*3+1], z = qb[qi*3+2];
        unsigned short hx = f2bf(x), hy = f2bf(y), hz = f2bf(z);
        unsigned short lx = f2bf(x - bf2f(hx));
        unsigned short ly = f2bf(y - bf2f(hy));
        unsigned short lz = f2bf(z - bf2f(hz));
        float a2 = fmaf(x,x, fmaf(y,y, z*z));
        unsigned short a2h = f2bf(a2);
        unsigned short a2l = f2bf(a2 - bf2f(a2h));
        if (lh == 0)
            af[qt] = (short8){ (short)hx,(short)hy,(short)hz,(short)lx,(short)ly,(short)lz,(short)hx,(short)hy };
        else
            af[qt] = (short8){ (short)hz, BF16_ONE, BF16_ONE, (short)a2h,(short)a2l, 0,0,0 };
    }
    __syncthreads();

    // ---- main loop: 32 iters x {2 B-tile reads, 8 MFMA, 64 min3} ----
    f32x16 mn[4], zero16;
    #pragma unroll
    for (int r = 0; r < 16; ++r) zero16[r] = 0.f;
    #pragma unroll
    for (int qt = 0; qt < 4; ++qt)
        #pragma unroll
        for (int r = 0; r < 16; ++r) mn[qt][r] = 3.4e38f;

    int boff = lr * 32 + lh * 16;
    #pragma unroll 2
    for (int t = 0; t < 32; ++t) {
        short8 b0 = *(const short8*)(smem + boff);
        short8 b1 = *(const short8*)(smem + boff + 1024);
        boff += 2048;
        #pragma unroll
        for (int qt = 0; qt < 4; ++qt) {
            f32x16 a0 = __builtin_amdgcn_mfma_f32_32x32x16_bf16(af[qt], b0, zero16, 0,0,0);
            f32x16 a1 = __builtin_amdgcn_mfma_f32_32x32x16_bf16(af[qt], b1, zero16, 0,0,0);
            #pragma unroll
            for (int r = 0; r < 16; ++r)
                mn[qt][r] = fminf(mn[qt][r], fminf(a0[r], a1[r]));   // v_min3
        }
    }

    // ---- epilogue: LDS transpose (stride 33, 2-way = free), per-thread tree ----
    __syncthreads();                       // done reading cands; reuse as sT
    float* sT = (float*)smem;
    #pragma unroll
    for (int qt = 0; qt < 4; ++qt)
        #pragma unroll
        for (int r = 0; r < 16; ++r) {
            const int q = wid * 128 + qt * 32 + ((r & 3) + 8 * (r >> 2) + 4 * lh);
            sT[q * TSTRIDE + lr] = mn[qt][r];
        }
    __syncthreads();

    float s = 0.f;
    #pragma unroll
    for (int k = 0; k < 2; ++k) {
        const float* row = sT + (tid + k * 256) * TSTRIDE;
        float m = fminf(row[0], row[1]);
        #pragma unroll
        for (int c = 2; c < 32; c += 2) m = fminf(m, fminf(row[c], row[c+1]));  // min3
        s += m;                            // a2 already folded via k11/k12
    }
    #pragma unroll
    for (int o = 32; o > 0; o >>= 1) s += __shfl_down(s, o, 64);
    if (lane == 0) wsum[wid] = s;
    __syncthreads();
    if (tid == 0) partial[blk] = (wsum[0] + wsum[1]) + (wsum[2] + wsum[3]);
}

// ---- kernel 2: 256-sum + cross-entropy + output ----------------------------
__global__ __launch_bounds__(256) void finalize_kernel(
    const float* __restrict__ partial, const float* __restrict__ pred,
    const int* __restrict__ gt, float* __restrict__ out)
{
    __shared__ float s_ce[BATCH];
    __shared__ float wsum[4];
    const int tid = threadIdx.x;

    float v = partial[tid];
    #pragma unroll
    for (int o = 32; o > 0; o >>= 1) v += __shfl_down(v, o, 64);
    const int lane = tid & 63, wid = tid >> 6;
    if (lane == 0) wsum[wid] = v;

    if (tid < BATCH) {
        const float* row = pred + tid * NUM_CLASSES;
        float mx = row[0];
        #pragma unroll
        for (int c = 1; c < NUM_CLASSES; ++c) mx = fmaxf(mx, row[c]);
        float se = 0.f;
        #pragma unroll
        for (int c = 0; c < NUM_CLASSES; ++c) se += __expf(row[c] - mx);
        const int lbl = gt[tid];
        s_ce[tid] = -(row[lbl] - mx - __logf(se));
    }
    __syncthreads();

    if (tid == 0) {
        float cd = ((wsum[0] + wsum[1]) + (wsum[2] + wsum[3])) / (float)(BATCH * NPTS);
        float ce = 0.f;
        for (int i = 0; i < BATCH; ++i) ce += s_ce[i];
        ce /= (float)BATCH;
        out[0] = 5.f * cd + ce;
        out[1] = cd;
        out[2] = ce;
    }
}

extern "C" void kernel_launch(void* const* d_in, const int* in_sizes, int n_in,
                              void* d_out, int out_size, void* d_ws, size_t ws_size,
                              hipStream_t stream) {
    const float* inst  = (const float*)d_in[0];
    const float* model = (const float*)d_in[1];
    const float* pred  = (const float*)d_in[2];
    const int*   gt    = (const int*)d_in[3];
    float* out     = (float*)d_out;
    float* partial = (float*)d_ws;   // 256 floats

    chamfer_pass1<<<GRID, THREADS, 0, stream>>>(inst, model, partial);
    finalize_kernel<<<1, 256, 0, stream>>>(partial, pred, gt, out);
}

// Round 9
// 27.079 us; speedup vs baseline: 1.3167x; 1.3167x over previous
//
#include <hip/hip_runtime.h>

typedef __attribute__((ext_vector_type(8)))  short short8;
typedef __attribute__((ext_vector_type(16))) float f32x16;

#define NPTS 2048
#define BATCH 32
#define NUM_CLASSES 6
#define THREADS 256
#define CHUNK 512             // candidates per LDS buffer
#define NCHUNK 4              // 2048 / 512
#define GRID 512              // 2 dirs * 32 batches * 8 query-chunks of 256
#define TSTRIDE 33
#define BF16_ONE ((short)0x3F80)
#define SMEM_BYTES 33792      // max(2*CHUNK*32 = 32768, 256*33*4 = 33792)

__device__ __forceinline__ unsigned short f2bf(float x) {
    union { float f; unsigned u; } v; v.f = x;
    unsigned r = v.u + 0x7FFF + ((v.u >> 16) & 1);   // RNE to bf16
    return (unsigned short)(r >> 16);
}
__device__ __forceinline__ float bf2f(unsigned short h) {
    union { unsigned u; float f; } v; v.u = ((unsigned)h) << 16; return v.f;
}

// Candidate -> B-frag (K-slot plan, absmax-0 verified R3-R8):
//  k0-2: -2bh | k3-5: -2bh | k6-8: -2bl | k9: b2h | k10: b2l | k11,k12: 1 | rest 0
__device__ __forceinline__ void stage_cand(char* dst, float bx, float by, float bz) {
    float m2x = -2.f*bx, m2y = -2.f*by, m2z = -2.f*bz;
    unsigned short hx = f2bf(m2x), hy = f2bf(m2y), hz = f2bf(m2z);
    unsigned short lx = f2bf(m2x - bf2f(hx));
    unsigned short ly = f2bf(m2y - bf2f(hy));
    unsigned short lz = f2bf(m2z - bf2f(hz));
    float b2 = fmaf(bx,bx, fmaf(by,by, bz*bz));
    unsigned short b2h = f2bf(b2);
    unsigned short b2l = f2bf(b2 - bf2f(b2h));
    short8 kg0 = { (short)hx,(short)hy,(short)hz,(short)hx,(short)hy,(short)hz,(short)lx,(short)ly };
    short8 kg1 = { (short)lz,(short)b2h,(short)b2l, BF16_ONE, BF16_ONE, 0,0,0 };
    *(short8*)(dst)      = kg0;
    *(short8*)(dst + 16) = kg1;
}

__global__ __launch_bounds__(THREADS, 3) void chamfer_pass1(
    const float* __restrict__ inst, const float* __restrict__ model,
    float* __restrict__ partial)
{
    __shared__ __align__(16) char smem[SMEM_BYTES];
    __shared__ float wsum[4];

    const int blk   = blockIdx.x;
    const int qcc   = blk & 7;
    const int batch = (blk >> 3) & 31;
    const int dir   = blk >> 8;
    const int tid   = threadIdx.x;
    const int lane  = tid & 63, wid = tid >> 6;
    const int lh    = lane >> 5, lr = lane & 31;

    const float* __restrict__ Q  = dir ? model : inst;
    const float* __restrict__ Cp = dir ? inst  : model;
    const float* cb = Cp + (size_t)batch * NPTS * 3;

    // ---- A-frags: 64 queries/wave, row = lane&31, k = (lane>>5)*8 + j ----
    //  k0-2: ah | k3-5: al | k6-8: ah | k9,k10: 1 | k11: a2h | k12: a2l | rest 0
    short8 af0, af1;
    const float* qb = Q + ((size_t)batch * NPTS + (size_t)qcc * 256) * 3;
    #pragma unroll
    for (int qt = 0; qt < 2; ++qt) {
        const int qi = (wid * 2 + qt) * 32 + lr;
        float x = qb[qi*3+0], y = qb[qi*3+1], z = qb[qi*3+2];
        unsigned short hx = f2bf(x), hy = f2bf(y), hz = f2bf(z);
        unsigned short lx = f2bf(x - bf2f(hx));
        unsigned short ly = f2bf(y - bf2f(hy));
        unsigned short lz = f2bf(z - bf2f(hz));
        float a2 = fmaf(x,x, fmaf(y,y, z*z));
        unsigned short a2h = f2bf(a2);
        unsigned short a2l = f2bf(a2 - bf2f(a2h));
        short8 f;
        if (lh == 0)
            f = (short8){ (short)hx,(short)hy,(short)hz,(short)lx,(short)ly,(short)lz,(short)hx,(short)hy };
        else
            f = (short8){ (short)hz, BF16_ONE, BF16_ONE, (short)a2h,(short)a2l, 0,0,0 };
        if (qt == 0) af0 = f; else af1 = f;
    }

    // ---- prologue: stage chunk 0 into buffer 0 ----
    // thread owns 2 consecutive cands: 6 floats at 8-B-aligned float2 boundaries
    {
        const float* src = cb + (size_t)tid * 6;
        float2 p0 = *(const float2*)(src + 0);
        float2 p1 = *(const float2*)(src + 2);
        float2 p2 = *(const float2*)(src + 4);
        stage_cand(smem + (tid*2  )*32, p0.x, p0.y, p1.x);
        stage_cand(smem + (tid*2+1)*32, p1.y, p2.x, p2.y);
    }
    __syncthreads();

    f32x16 mn, mn2, zero16;
    #pragma unroll
    for (int r = 0; r < 16; ++r) { mn[r] = 3.4e38f; mn2[r] = 3.4e38f; zero16[r] = 0.f; }

    // ---- main: 4 chunks, double-buffered; T14 split (load early, write late) ----
    for (int ch = 0; ch < NCHUNK; ++ch) {
        float2 p0, p1, p2;
        if (ch < NCHUNK - 1) {               // issue next chunk's loads early
            const float* src = cb + ((size_t)(ch + 1) * CHUNK + (size_t)tid * 2) * 3;
            p0 = *(const float2*)(src + 0);
            p1 = *(const float2*)(src + 2);
            p2 = *(const float2*)(src + 4);
        }

        const char* cbuf = smem + (ch & 1) * (CHUNK * 32);
        int boff = lr * 32 + lh * 16;
        #pragma unroll 2
        for (int t = 0; t < 8; ++t) {
            short8 b0 = *(const short8*)(cbuf + boff);
            short8 b1 = *(const short8*)(cbuf + boff + 1024);
            boff += 2048;
            f32x16 a00 = __builtin_amdgcn_mfma_f32_32x32x16_bf16(af0, b0, zero16, 0,0,0);
            f32x16 a01 = __builtin_amdgcn_mfma_f32_32x32x16_bf16(af0, b1, zero16, 0,0,0);
            f32x16 a10 = __builtin_amdgcn_mfma_f32_32x32x16_bf16(af1, b0, zero16, 0,0,0);
            f32x16 a11 = __builtin_amdgcn_mfma_f32_32x32x16_bf16(af1, b1, zero16, 0,0,0);
            #pragma unroll
            for (int r = 0; r < 16; ++r) mn[r]  = fminf(mn[r],  fminf(a00[r], a01[r]));  // v_min3
            #pragma unroll
            for (int r = 0; r < 16; ++r) mn2[r] = fminf(mn2[r], fminf(a10[r], a11[r]));
        }

        if (ch < NCHUNK - 1) {               // write next chunk after compute
            char* nbuf = smem + ((ch + 1) & 1) * (CHUNK * 32);
            stage_cand(nbuf + (tid*2  )*32, p0.x, p0.y, p1.x);
            stage_cand(nbuf + (tid*2+1)*32, p1.y, p2.x, p2.y);
        }
        __syncthreads();
    }

    // ---- epilogue: stride-33 LDS transpose + per-thread min tree ----
    // D layout: col(cand) = lane&31, row(query) = (r&3) + 8*(r>>2) + 4*lh
    float* sT = (float*)smem;
    #pragma unroll
    for (int r = 0; r < 16; ++r) {
        const int q0 = wid * 64 + ((r & 3) + 8 * (r >> 2) + 4 * lh);
        sT[q0 * TSTRIDE + lr] = mn[r];
    }
    #pragma unroll
    for (int r = 0; r < 16; ++r) {
        const int q1 = wid * 64 + 32 + ((r & 3) + 8 * (r >> 2) + 4 * lh);
        sT[q1 * TSTRIDE + lr] = mn2[r];
    }
    __syncthreads();

    const float* row = sT + tid * TSTRIDE;
    float m = fminf(row[0], row[1]);
    #pragma unroll
    for (int c = 2; c < 32; c += 2) m = fminf(m, fminf(row[c], row[c+1]));  // v_min3
    float s = m;                       // a2 folded in-MFMA (k11/k12)
    #pragma unroll
    for (int o = 32; o > 0; o >>= 1) s += __shfl_down(s, o, 64);
    if (lane == 0) wsum[wid] = s;
    __syncthreads();
    if (tid == 0) partial[blk] = (wsum[0] + wsum[1]) + (wsum[2] + wsum[3]);
}

// ---- kernel 2: 512-sum + cross-entropy + output ----------------------------
__global__ __launch_bounds__(256) void finalize_kernel(
    const float* __restrict__ partial, const float* __restrict__ pred,
    const int* __restrict__ gt, float* __restrict__ out)
{
    __shared__ float s_ce[BATCH];
    __shared__ float wsum[4];
    const int tid = threadIdx.x;

    float v = partial[tid] + partial[tid + 256];
    #pragma unroll
    for (int o = 32; o > 0; o >>= 1) v += __shfl_down(v, o, 64);
    const int lane = tid & 63, wid = tid >> 6;
    if (lane == 0) wsum[wid] = v;

    if (tid < BATCH) {
        const float* row = pred + tid * NUM_CLASSES;
        float mx = row[0];
        #pragma unroll
        for (int c = 1; c < NUM_CLASSES; ++c) mx = fmaxf(mx, row[c]);
        float se = 0.f;
        #pragma unroll
        for (int c = 0; c < NUM_CLASSES; ++c) se += __expf(row[c] - mx);
        const int lbl = gt[tid];
        s_ce[tid] = -(row[lbl] - mx - __logf(se));
    }
    __syncthreads();

    if (tid == 0) {
        float cd = ((wsum[0] + wsum[1]) + (wsum[2] + wsum[3])) / (float)(BATCH * NPTS);
        float ce = 0.f;
        for (int i = 0; i < BATCH; ++i) ce += s_ce[i];
        ce /= (float)BATCH;
        out[0] = 5.f * cd + ce;
        out[1] = cd;
        out[2] = ce;
    }
}

extern "C" void kernel_launch(void* const* d_in, const int* in_sizes, int n_in,
                              void* d_out, int out_size, void* d_ws, size_t ws_size,
                              hipStream_t stream) {
    const float* inst  = (const float*)d_in[0];
    const float* model = (const float*)d_in[1];
    const float* pred  = (const float*)d_in[2];
    const int*   gt    = (const int*)d_in[3];
    float* out     = (float*)d_out;
    float* partial = (float*)d_ws;   // 512 floats

    chamfer_pass1<<<GRID, THREADS, 0, stream>>>(inst, model, partial);
    finalize_kernel<<<1, 256, 0, stream>>>(partial, pred, gt, out);
}